// Round 10
// baseline (352.225 us; speedup 1.0000x reference)
//
#include <hip/hip_runtime.h>
#include <hip/hip_bf16.h>

#define NB 8
#define PP 256
#define CC 128
#define XS 132     // padded row stride for f32 LDS tiles

typedef _Float16 f16x8 __attribute__((ext_vector_type(8)));
typedef _Float16 h2v __attribute__((ext_vector_type(2)));
typedef float float4v __attribute__((ext_vector_type(4)));

__device__ __forceinline__ float bf2f(unsigned short u) {
    union { unsigned int i; float f; } x; x.i = ((unsigned int)u) << 16; return x.f;
}
__device__ __forceinline__ unsigned short f2bf(float f) {
    union { float f; unsigned int i; } x; x.f = f;
    unsigned int r = x.i + 0x7fffu + ((x.i >> 16) & 1u);  // RNE
    return (unsigned short)(r >> 16);
}
__device__ __forceinline__ unsigned short f2h(float f) {
    union { _Float16 h; unsigned short u; } cv; cv.h = (_Float16)f; return cv.u;
}

// ONE prologue kernel, 197 blocks x 256 threads:
//  0..63   q: qwtb[n][j][b] = bf16( ((x@Wq)@W1)[b][j] )   (transposed)
//  64..127 k: kw = (x@Wk)@W1  (f32)
//  128..191 v: v = x@Wv       (f32)
//  192..195 W21f = (Wp2@W1) in fp16 MFMA-fragment order
//  196     bvec[j] = b1[j] + bp2@W1
__global__ __launch_bounds__(256) void stage1_kernel(
    const float* __restrict__ x, const float* __restrict__ Wq,
    const float* __restrict__ Wk, const float* __restrict__ Wv,
    const float* __restrict__ W1, const float* __restrict__ b1,
    const float* __restrict__ bp2, const float* __restrict__ Wp2,
    unsigned short* __restrict__ qwtb, float* __restrict__ kw,
    float* __restrict__ v, unsigned short* __restrict__ W21f,
    float* __restrict__ bvec)
{
    __shared__ float Wbuf[CC * CC];    // 64 KB
    __shared__ float xs[32 * XS];      // ~17 KB
    __shared__ float tmp[32 * XS];     // ~17 KB
    const int t = threadIdx.x, bx = blockIdx.x;

    if (bx == 196) {
        if (t < 128) {
            float s = b1[t];
#pragma unroll 8
            for (int c = 0; c < CC; ++c) s = fmaf(bp2[c], W1[c * CC + t], s);
            bvec[t] = s;
        }
        return;
    }

    const int tc = t & 31, tr = t >> 5;
    const int j0 = tc * 4, r0 = tr * 4;

    if (bx < 192) {
        const int kind = bx >> 6;            // 0=q, 1=k, 2=v
        const int row0 = (bx & 63) * 32;
        const float* Wsrc = (kind == 0) ? Wq : (kind == 1) ? Wk : Wv;
#pragma unroll 8
        for (int i = 0; i < 64; ++i) Wbuf[i * 256 + t] = Wsrc[i * 256 + t];
#pragma unroll 4
        for (int i = 0; i < 16; ++i) {
            int idx = i * 256 + t; int r = idx >> 7, c = idx & 127;
            xs[r * XS + c] = x[(size_t)(row0 + r) * CC + c];
        }
        __syncthreads();
        float acc[4][4];
#pragma unroll
        for (int i = 0; i < 4; ++i)
#pragma unroll
            for (int jj = 0; jj < 4; ++jj) acc[i][jj] = 0.f;
#pragma unroll 2
        for (int c = 0; c < CC; ++c) {
            float4 w4 = *(const float4*)&Wbuf[c * CC + j0];
#pragma unroll
            for (int i = 0; i < 4; ++i) {
                float xv = xs[(r0 + i) * XS + c];
                acc[i][0] = fmaf(xv, w4.x, acc[i][0]); acc[i][1] = fmaf(xv, w4.y, acc[i][1]);
                acc[i][2] = fmaf(xv, w4.z, acc[i][2]); acc[i][3] = fmaf(xv, w4.w, acc[i][3]);
            }
        }
        if (kind == 2) {
#pragma unroll
            for (int i = 0; i < 4; ++i)
                *(float4*)&v[(size_t)(row0 + r0 + i) * CC + j0] =
                    make_float4(acc[i][0], acc[i][1], acc[i][2], acc[i][3]);
            return;
        }
        // write tmp, restage Wbuf with W1, second GEMM
#pragma unroll
        for (int i = 0; i < 4; ++i)
#pragma unroll
            for (int jj = 0; jj < 4; ++jj) tmp[(r0 + i) * XS + j0 + jj] = acc[i][jj];
        __syncthreads();
#pragma unroll 8
        for (int i = 0; i < 64; ++i) Wbuf[i * 256 + t] = W1[i * 256 + t];
        __syncthreads();
        float acc2[4][4];
#pragma unroll
        for (int i = 0; i < 4; ++i)
#pragma unroll
            for (int jj = 0; jj < 4; ++jj) acc2[i][jj] = 0.f;
#pragma unroll 2
        for (int c = 0; c < CC; ++c) {
            float4 w4 = *(const float4*)&Wbuf[c * CC + j0];
#pragma unroll
            for (int i = 0; i < 4; ++i) {
                float xv = tmp[(r0 + i) * XS + c];
                acc2[i][0] = fmaf(xv, w4.x, acc2[i][0]); acc2[i][1] = fmaf(xv, w4.y, acc2[i][1]);
                acc2[i][2] = fmaf(xv, w4.z, acc2[i][2]); acc2[i][3] = fmaf(xv, w4.w, acc2[i][3]);
            }
        }
        if (kind == 0) {
            int n = row0 >> 8, b0 = row0 & 255;
#pragma unroll
            for (int jj = 0; jj < 4; ++jj) {
                ushort4 pk;
                pk.x = f2bf(acc2[0][jj]); pk.y = f2bf(acc2[1][jj]);
                pk.z = f2bf(acc2[2][jj]); pk.w = f2bf(acc2[3][jj]);
                *(ushort4*)(qwtb + (size_t)(n * CC + j0 + jj) * PP + b0 + r0) = pk;
            }
        } else {
#pragma unroll
            for (int i = 0; i < 4; ++i)
                *(float4*)&kw[(size_t)(row0 + r0 + i) * CC + j0] =
                    make_float4(acc2[i][0], acc2[i][1], acc2[i][2], acc2[i][3]);
        }
    } else {
        // W21f: rows of Wp2 @ W1, stored fp16 fragment order
        const int row0 = (bx - 192) * 32;
#pragma unroll 8
        for (int i = 0; i < 64; ++i) Wbuf[i * 256 + t] = W1[i * 256 + t];
#pragma unroll 4
        for (int i = 0; i < 16; ++i) {
            int idx = i * 256 + t; int r = idx >> 7, c = idx & 127;
            xs[r * XS + c] = Wp2[(size_t)(row0 + r) * CC + c];
        }
        __syncthreads();
        float acc[4][4];
#pragma unroll
        for (int i = 0; i < 4; ++i)
#pragma unroll
            for (int jj = 0; jj < 4; ++jj) acc[i][jj] = 0.f;
#pragma unroll 2
        for (int c = 0; c < CC; ++c) {
            float4 w4 = *(const float4*)&Wbuf[c * CC + j0];
#pragma unroll
            for (int i = 0; i < 4; ++i) {
                float xv = xs[(r0 + i) * XS + c];
                acc[i][0] = fmaf(xv, w4.x, acc[i][0]); acc[i][1] = fmaf(xv, w4.y, acc[i][1]);
                acc[i][2] = fmaf(xv, w4.z, acc[i][2]); acc[i][3] = fmaf(xv, w4.w, acc[i][3]);
            }
        }
#pragma unroll
        for (int i = 0; i < 4; ++i)
#pragma unroll
            for (int jj = 0; jj < 4; ++jj) {
                int k = row0 + r0 + i, j = j0 + jj;
                int kk = k >> 5, qd = (k >> 3) & 3, e = k & 7;
                int jt = j >> 4, ln = j & 15, lane = qd * 16 + ln;
                W21f[(((kk * 8 + jt) * 64) + lane) * 8 + e] = f2h(acc[i][jj]);
            }
    }
}

// One block per (n,a). fp16 MFMA; A built in regs (constants fully in VGPRs —
// kk loop FULLY unrolled so no runtime-indexed arrays / scratch demotion);
// B in fragment-order LDS (conflict-free b128); AV loop float4-vectorized.
__global__ __launch_bounds__(256, 3) void attn_kernel(
    const float* __restrict__ x, const float* __restrict__ pos,
    const float* __restrict__ Wp1, const float* __restrict__ bp1,
    const float* __restrict__ W2, const float* __restrict__ b2,
    const unsigned short* __restrict__ W21f, const float* __restrict__ bvec,
    const unsigned short* __restrict__ qwtb, const float* __restrict__ kw,
    const float* __restrict__ v, float* __restrict__ out)
{
    __shared__ __attribute__((aligned(16))) unsigned short Bs[128 * 128]; // frag order
    __shared__ float p0s[PP], p1s[PP];
    __shared__ float logits[PP];
    __shared__ float red[8];
    __shared__ float avp[8 * 128];

    const int t = threadIdx.x;
    const int n = blockIdx.x >> 8, a = blockIdx.x & 255;
    const int lane = t & 63, wv = t >> 6;
    const int ln = lane & 15, quad = lane >> 4;

    {
        const float2* pr = (const float2*)(pos + (size_t)(n * PP + a) * PP * 2);
        float2 pp = pr[t];
        p0s[t] = pp.x;
        p1s[t] = pp.y;
    }
    {   // stage Bs: straight 16B copies (global coalesced, LDS conflict-free)
        const uint4* src = (const uint4*)W21f;
        uint4* dst = (uint4*)Bs;
#pragma unroll
        for (int i = 0; i < 8; ++i) dst[i * 256 + t] = src[i * 256 + t];
    }
    const float b2f = b2[0];

    // A-operand constants in registers (constant-indexed everywhere)
    h2v wa2[16], wb2[16], bp2h[16];
#pragma unroll
    for (int kk = 0; kk < 4; ++kk)
#pragma unroll
        for (int p = 0; p < 4; ++p) {
            int k = kk * 32 + quad * 8 + p * 2;
            wa2[kk * 4 + p]  = (h2v){(_Float16)Wp1[k],      (_Float16)Wp1[k + 1]};
            wb2[kk * 4 + p]  = (h2v){(_Float16)Wp1[CC + k], (_Float16)Wp1[CC + k + 1]};
            bp2h[kk * 4 + p] = (h2v){(_Float16)bp1[k],      (_Float16)bp1[k + 1]};
        }

    // per-lane epilogue constants (col j = nt*16 + ln)
    float w2v[8], kbv[8];
    {
        const float* kwrow = kw + (size_t)(n * PP + a) * CC;
#pragma unroll
        for (int nt = 0; nt < 8; ++nt) {
            int j = nt * 16 + ln;
            w2v[nt] = W2[j];
            kbv[nt] = bvec[j] - kwrow[j];
        }
    }
    const h2v z2 = (h2v){(_Float16)0.f, (_Float16)0.f};
    __syncthreads();

#pragma unroll 1
    for (int chunk = 0; chunk < 4; ++chunk) {
        const int rbase = chunk * 64 + wv * 16;
        const _Float16 p0h = (_Float16)p0s[rbase + ln];
        const _Float16 p1h = (_Float16)p1s[rbase + ln];
        const h2v P0h = (h2v){p0h, p0h};
        const h2v P1h = (h2v){p1h, p1h};

        // prefetch qw epilogue values (bf16 transposed [n][j][b])
        ushort4 qv4[8];
#pragma unroll
        for (int nt = 0; nt < 8; ++nt)
            qv4[nt] = *(const ushort4*)(qwtb + (size_t)(n * CC + nt * 16 + ln) * PP
                                        + rbase + quad * 4);

        float4v acc[8];
#pragma unroll
        for (int j = 0; j < 8; ++j) acc[j] = (float4v)0.f;

#pragma unroll
        for (int kk = 0; kk < 4; ++kk) {
            union { f16x8 v8; h2v h2[4]; } A;
#pragma unroll
            for (int p = 0; p < 4; ++p)
                A.h2[p] = __builtin_elementwise_max(
                    P0h * wa2[kk * 4 + p] + P1h * wb2[kk * 4 + p] + bp2h[kk * 4 + p], z2);
#pragma unroll
            for (int j = 0; j < 8; ++j) {
                f16x8 bfr = *(const f16x8*)(Bs + (((kk * 8 + j) * 64) + lane) * 8);
                acc[j] = __builtin_amdgcn_mfma_f32_16x16x32_f16(A.v8, bfr, acc[j], 0, 0, 0);
            }
        }

        // epilogue: D row = quad*4 + r, col = nt*16 + ln
        float s0 = 0.f, s1 = 0.f, s2 = 0.f, s3 = 0.f;
#pragma unroll
        for (int nt = 0; nt < 8; ++nt) {
            float kb = kbv[nt], w2 = w2v[nt];
            s0 = fmaf(fmaxf(acc[nt][0] + bf2f(qv4[nt].x) + kb, 0.f), w2, s0);
            s1 = fmaf(fmaxf(acc[nt][1] + bf2f(qv4[nt].y) + kb, 0.f), w2, s1);
            s2 = fmaf(fmaxf(acc[nt][2] + bf2f(qv4[nt].z) + kb, 0.f), w2, s2);
            s3 = fmaf(fmaxf(acc[nt][3] + bf2f(qv4[nt].w) + kb, 0.f), w2, s3);
        }
        float sr[4] = {s0, s1, s2, s3};
#pragma unroll
        for (int r = 0; r < 4; ++r) {
            float s = sr[r];
            s += __shfl_xor(s, 1);
            s += __shfl_xor(s, 2);
            s += __shfl_xor(s, 4);
            s += __shfl_xor(s, 8);
            if (ln == 0) logits[rbase + quad * 4 + r] = s + b2f;
        }
    }
    __syncthreads();   // logits ready

    // ---- softmax over 256 logits: wave shfl reductions ----
    float lv = logits[t];
    float wm = lv;
#pragma unroll
    for (int d = 1; d < 64; d <<= 1) wm = fmaxf(wm, __shfl_xor(wm, d));
    if (lane == 0) red[wv] = wm;
    __syncthreads();
    float m = fmaxf(fmaxf(red[0], red[1]), fmaxf(red[2], red[3]));
    float e = __expf(lv - m);
    float es = e;
#pragma unroll
    for (int d = 1; d < 64; d <<= 1) es += __shfl_xor(es, d);
    if (lane == 0) red[4 + wv] = es;
    __syncthreads();
    float denom = red[4] + red[5] + red[6] + red[7];
    logits[t] = e / denom;
    __syncthreads();

    // ---- out[n,a,c] = x[n,a,c] + sum_b att[b] * v[n,b,c], float4 over c ----
    {
        int c4 = (t & 31) * 4, bg = t >> 5;          // 8 b-groups of 32
        const float* vp = v + (size_t)(n * PP + bg * 32) * CC + c4;
        float4 av = make_float4(0.f, 0.f, 0.f, 0.f);
#pragma unroll 4
        for (int b = 0; b < 32; ++b) {
            float w = logits[bg * 32 + b];
            float4 vv = *(const float4*)(vp + (size_t)b * CC);
            av.x = fmaf(w, vv.x, av.x); av.y = fmaf(w, vv.y, av.y);
            av.z = fmaf(w, vv.z, av.z); av.w = fmaf(w, vv.w, av.w);
        }
        *(float4*)&avp[bg * 128 + c4] = av;
    }
    __syncthreads();
    if (t < 128) {
        int oidx = (n * PP + a) * CC + t;
        float s = x[oidx];
#pragma unroll
        for (int g = 0; g < 8; ++g) s += avp[g * 128 + t];
        out[oidx] = s;
    }
}

extern "C" void kernel_launch(void* const* d_in, const int* in_sizes, int n_in,
                              void* d_out, int out_size, void* d_ws, size_t ws_size,
                              hipStream_t stream) {
    const float* x   = (const float*)d_in[0];
    const float* pos = (const float*)d_in[1];
    const float* Wq  = (const float*)d_in[2];
    const float* Wk  = (const float*)d_in[3];
    const float* Wv  = (const float*)d_in[4];
    const float* W1  = (const float*)d_in[5];
    const float* b1  = (const float*)d_in[6];
    const float* W2  = (const float*)d_in[7];
    const float* b2  = (const float*)d_in[8];
    const float* Wp1 = (const float*)d_in[9];
    const float* bp1 = (const float*)d_in[10];
    const float* Wp2 = (const float*)d_in[11];
    const float* bp2 = (const float*)d_in[12];
    float* out = (float*)d_out;

    float* ws   = (float*)d_ws;
    float* bvec = ws;                  // 128 f32
    float* kw   = bvec + 128;          // 262144 f32
    float* v    = kw + 262144;         // 262144 f32
    unsigned short* qwtb = (unsigned short*)(v + 262144);  // 262144 bf16
    unsigned short* W21f = qwtb + 262144;                  // 16384 fp16 (frag order)

    stage1_kernel<<<197, 256, 0, stream>>>(x, Wq, Wk, Wv, W1, b1, bp2, Wp2,
                                           qwtb, kw, v, W21f, bvec);
    attn_kernel<<<NB * PP, 256, 0, stream>>>(x, pos, Wp1, bp1, W2, b2,
                                             W21f, bvec, qwtb, kw, v, out);
}

// Round 11
// 147.603 us; speedup vs baseline: 2.3863x; 2.3863x over previous
//
#include <hip/hip_runtime.h>
#include <hip/hip_bf16.h>

#define NB 8
#define PP 256
#define CC 128
#define XS 132     // padded row stride for f32 LDS tiles

typedef __attribute__((ext_vector_type(8))) unsigned short ushort8;
typedef __bf16 bf16x8 __attribute__((ext_vector_type(8)));
typedef float float4v __attribute__((ext_vector_type(4)));

__device__ __forceinline__ float bf2f(unsigned short u) {
    union { unsigned int i; float f; } x; x.i = ((unsigned int)u) << 16; return x.f;
}
__device__ __forceinline__ unsigned short f2bf(float f) {
    union { float f; unsigned int i; } x; x.f = f;
    unsigned int r = x.i + 0x7fffu + ((x.i >> 16) & 1u);  // RNE
    return (unsigned short)(r >> 16);
}
__device__ __forceinline__ unsigned int pk2(float a, float b) {
    return (unsigned int)f2bf(a) | ((unsigned int)f2bf(b) << 16);
}

// ONE prologue kernel, 197 blocks x 256 threads:
//  0..63   q: qwtb[n][j][b] = bf16( ((x@Wq)@W1)[b][j] )   (transposed)
//  64..127 k: kw = (x@Wk)@W1  (f32)
//  128..191 v: v = x@Wv       (f32)
//  192..195 W21f = (Wp2@W1) in bf16 MFMA-fragment order
//  196     bvec[j] = b1[j] + bp2@W1
__global__ __launch_bounds__(256) void stage1_kernel(
    const float* __restrict__ x, const float* __restrict__ Wq,
    const float* __restrict__ Wk, const float* __restrict__ Wv,
    const float* __restrict__ W1, const float* __restrict__ b1,
    const float* __restrict__ bp2, const float* __restrict__ Wp2,
    unsigned short* __restrict__ qwtb, float* __restrict__ kw,
    float* __restrict__ v, unsigned short* __restrict__ W21f,
    float* __restrict__ bvec)
{
    __shared__ float Wbuf[CC * CC];    // 64 KB
    __shared__ float xs[32 * XS];
    __shared__ float tmp[32 * XS];
    const int t = threadIdx.x, bx = blockIdx.x;

    if (bx == 196) {
        if (t < 128) {
            float s = b1[t];
#pragma unroll 8
            for (int c = 0; c < CC; ++c) s = fmaf(bp2[c], W1[c * CC + t], s);
            bvec[t] = s;
        }
        return;
    }

    const int tc = t & 31, tr = t >> 5;
    const int j0 = tc * 4, r0 = tr * 4;

    if (bx < 192) {
        const int kind = bx >> 6;            // 0=q, 1=k, 2=v
        const int row0 = (bx & 63) * 32;
        const float* Wsrc = (kind == 0) ? Wq : (kind == 1) ? Wk : Wv;
#pragma unroll 8
        for (int i = 0; i < 64; ++i) Wbuf[i * 256 + t] = Wsrc[i * 256 + t];
#pragma unroll 4
        for (int i = 0; i < 16; ++i) {
            int idx = i * 256 + t; int r = idx >> 7, c = idx & 127;
            xs[r * XS + c] = x[(size_t)(row0 + r) * CC + c];
        }
        __syncthreads();
        float acc[4][4];
#pragma unroll
        for (int i = 0; i < 4; ++i)
#pragma unroll
            for (int jj = 0; jj < 4; ++jj) acc[i][jj] = 0.f;
#pragma unroll 2
        for (int c = 0; c < CC; ++c) {
            float4 w4 = *(const float4*)&Wbuf[c * CC + j0];
#pragma unroll
            for (int i = 0; i < 4; ++i) {
                float xv = xs[(r0 + i) * XS + c];
                acc[i][0] = fmaf(xv, w4.x, acc[i][0]); acc[i][1] = fmaf(xv, w4.y, acc[i][1]);
                acc[i][2] = fmaf(xv, w4.z, acc[i][2]); acc[i][3] = fmaf(xv, w4.w, acc[i][3]);
            }
        }
        if (kind == 2) {
#pragma unroll
            for (int i = 0; i < 4; ++i)
                *(float4*)&v[(size_t)(row0 + r0 + i) * CC + j0] =
                    make_float4(acc[i][0], acc[i][1], acc[i][2], acc[i][3]);
            return;
        }
        // write tmp, restage Wbuf with W1, second GEMM
#pragma unroll
        for (int i = 0; i < 4; ++i)
#pragma unroll
            for (int jj = 0; jj < 4; ++jj) tmp[(r0 + i) * XS + j0 + jj] = acc[i][jj];
        __syncthreads();
#pragma unroll 8
        for (int i = 0; i < 64; ++i) Wbuf[i * 256 + t] = W1[i * 256 + t];
        __syncthreads();
        float acc2[4][4];
#pragma unroll
        for (int i = 0; i < 4; ++i)
#pragma unroll
            for (int jj = 0; jj < 4; ++jj) acc2[i][jj] = 0.f;
#pragma unroll 2
        for (int c = 0; c < CC; ++c) {
            float4 w4 = *(const float4*)&Wbuf[c * CC + j0];
#pragma unroll
            for (int i = 0; i < 4; ++i) {
                float xv = tmp[(r0 + i) * XS + c];
                acc2[i][0] = fmaf(xv, w4.x, acc2[i][0]); acc2[i][1] = fmaf(xv, w4.y, acc2[i][1]);
                acc2[i][2] = fmaf(xv, w4.z, acc2[i][2]); acc2[i][3] = fmaf(xv, w4.w, acc2[i][3]);
            }
        }
        if (kind == 0) {
            int n = row0 >> 8, b0 = row0 & 255;
#pragma unroll
            for (int jj = 0; jj < 4; ++jj) {
                ushort4 pk;
                pk.x = f2bf(acc2[0][jj]); pk.y = f2bf(acc2[1][jj]);
                pk.z = f2bf(acc2[2][jj]); pk.w = f2bf(acc2[3][jj]);
                *(ushort4*)(qwtb + (size_t)(n * CC + j0 + jj) * PP + b0 + r0) = pk;
            }
        } else {
#pragma unroll
            for (int i = 0; i < 4; ++i)
                *(float4*)&kw[(size_t)(row0 + r0 + i) * CC + j0] =
                    make_float4(acc2[i][0], acc2[i][1], acc2[i][2], acc2[i][3]);
        }
    } else {
        // W21f: rows of Wp2 @ W1, stored bf16 fragment order
        const int row0 = (bx - 192) * 32;
#pragma unroll 8
        for (int i = 0; i < 64; ++i) Wbuf[i * 256 + t] = W1[i * 256 + t];
#pragma unroll 4
        for (int i = 0; i < 16; ++i) {
            int idx = i * 256 + t; int r = idx >> 7, c = idx & 127;
            xs[r * XS + c] = Wp2[(size_t)(row0 + r) * CC + c];
        }
        __syncthreads();
        float acc[4][4];
#pragma unroll
        for (int i = 0; i < 4; ++i)
#pragma unroll
            for (int jj = 0; jj < 4; ++jj) acc[i][jj] = 0.f;
#pragma unroll 2
        for (int c = 0; c < CC; ++c) {
            float4 w4 = *(const float4*)&Wbuf[c * CC + j0];
#pragma unroll
            for (int i = 0; i < 4; ++i) {
                float xv = xs[(r0 + i) * XS + c];
                acc[i][0] = fmaf(xv, w4.x, acc[i][0]); acc[i][1] = fmaf(xv, w4.y, acc[i][1]);
                acc[i][2] = fmaf(xv, w4.z, acc[i][2]); acc[i][3] = fmaf(xv, w4.w, acc[i][3]);
            }
        }
#pragma unroll
        for (int i = 0; i < 4; ++i)
#pragma unroll
            for (int jj = 0; jj < 4; ++jj) {
                int k = row0 + r0 + i, j = j0 + jj;
                int kk = k >> 5, qd = (k >> 3) & 3, e = k & 7;
                int jt = j >> 4, ln = j & 15, lane = qd * 16 + ln;
                W21f[(((kk * 8 + jt) * 64) + lane) * 8 + e] = f2bf(acc[i][jj]);
            }
    }
}

// One block per (n,a). R7-proven structure: A built per-kk from LDS broadcast
// float4 reads (quad-uniform -> free), bf16 pk2 pack, bf16 MFMA; B in
// fragment-order LDS (zero conflicts); float4 AV epilogue.
__global__ __launch_bounds__(256, 3) void attn_kernel(
    const float* __restrict__ x, const float* __restrict__ pos,
    const float* __restrict__ Wp1, const float* __restrict__ bp1,
    const float* __restrict__ W2, const float* __restrict__ b2,
    const unsigned short* __restrict__ W21f, const float* __restrict__ bvec,
    const unsigned short* __restrict__ qwtb, const float* __restrict__ kw,
    const float* __restrict__ v, float* __restrict__ out)
{
    __shared__ __attribute__((aligned(16))) unsigned short Bs[128 * 128]; // frag order
    __shared__ float p0s[PP], p1s[PP];
    __shared__ float wa[CC], wb[CC], bpv[CC];
    __shared__ float logits[PP];
    __shared__ float red[8];
    __shared__ float avp[8 * 128];

    const int t = threadIdx.x;
    const int n = blockIdx.x >> 8, a = blockIdx.x & 255;
    const int lane = t & 63, wv = t >> 6;
    const int ln = lane & 15, quad = lane >> 4;

    if (t < CC) {
        wa[t]  = Wp1[t];
        wb[t]  = Wp1[CC + t];
        bpv[t] = bp1[t];
    }
    {
        const float2* pr = (const float2*)(pos + (size_t)(n * PP + a) * PP * 2);
        float2 pp = pr[t];
        p0s[t] = pp.x;
        p1s[t] = pp.y;
    }
    {   // stage Bs: straight 16B copies (global coalesced, LDS conflict-free)
        const uint4* src = (const uint4*)W21f;
        uint4* dst = (uint4*)Bs;
#pragma unroll
        for (int i = 0; i < 8; ++i) dst[i * 256 + t] = src[i * 256 + t];
    }
    const float b2f = b2[0];

    // per-lane epilogue constants (col j = nt*16 + ln)
    float w2v[8], kbv[8];
    {
        const float* kwrow = kw + (size_t)(n * PP + a) * CC;
#pragma unroll
        for (int nt = 0; nt < 8; ++nt) {
            int j = nt * 16 + ln;
            w2v[nt] = W2[j];
            kbv[nt] = bvec[j] - kwrow[j];
        }
    }
    __syncthreads();

#pragma unroll 1
    for (int chunk = 0; chunk < 4; ++chunk) {
        const int rbase = chunk * 64 + wv * 16;
        const float P0 = p0s[rbase + ln];
        const float P1 = p1s[rbase + ln];

        // prefetch qw epilogue values (bf16 transposed [n][j][b]) — drains behind MFMA
        ushort4 qv4[8];
#pragma unroll
        for (int nt = 0; nt < 8; ++nt)
            qv4[nt] = *(const ushort4*)(qwtb + (size_t)(n * CC + nt * 16 + ln) * PP
                                        + rbase + quad * 4);

        float4v acc[8];
#pragma unroll
        for (int j = 0; j < 8; ++j) acc[j] = (float4v)0.f;

#pragma unroll 1
        for (int kk = 0; kk < 4; ++kk) {
            const int ko = kk * 32 + quad * 8;
            // A-fragment in registers from LDS broadcast reads: A[m=ln][k=ko+e]
            float4 a0 = *(const float4*)&wa[ko],  a1 = *(const float4*)&wa[ko + 4];
            float4 c0 = *(const float4*)&wb[ko],  c1 = *(const float4*)&wb[ko + 4];
            float4 d0 = *(const float4*)&bpv[ko], d1 = *(const float4*)&bpv[ko + 4];
            float h0 = fmaxf(fmaf(P0, a0.x, fmaf(P1, c0.x, d0.x)), 0.f);
            float h1 = fmaxf(fmaf(P0, a0.y, fmaf(P1, c0.y, d0.y)), 0.f);
            float h2 = fmaxf(fmaf(P0, a0.z, fmaf(P1, c0.z, d0.z)), 0.f);
            float h3 = fmaxf(fmaf(P0, a0.w, fmaf(P1, c0.w, d0.w)), 0.f);
            float h4 = fmaxf(fmaf(P0, a1.x, fmaf(P1, c1.x, d1.x)), 0.f);
            float h5 = fmaxf(fmaf(P0, a1.y, fmaf(P1, c1.y, d1.y)), 0.f);
            float h6 = fmaxf(fmaf(P0, a1.z, fmaf(P1, c1.z, d1.z)), 0.f);
            float h7 = fmaxf(fmaf(P0, a1.w, fmaf(P1, c1.w, d1.w)), 0.f);
            union { bf16x8 v8; unsigned int u[4]; } cv;
            cv.u[0] = pk2(h0, h1); cv.u[1] = pk2(h2, h3);
            cv.u[2] = pk2(h4, h5); cv.u[3] = pk2(h6, h7);
            bf16x8 af = cv.v8;
#pragma unroll
            for (int j = 0; j < 8; ++j) {
                bf16x8 bfr = *(const bf16x8*)(Bs + (((kk * 8 + j) * 64) + lane) * 8);
                acc[j] = __builtin_amdgcn_mfma_f32_16x16x32_bf16(af, bfr, acc[j], 0, 0, 0);
            }
        }

        // epilogue: D row = quad*4 + r, col = nt*16 + ln
        float s0 = 0.f, s1 = 0.f, s2 = 0.f, s3 = 0.f;
#pragma unroll
        for (int nt = 0; nt < 8; ++nt) {
            float kb = kbv[nt], w2 = w2v[nt];
            s0 = fmaf(fmaxf(acc[nt][0] + bf2f(qv4[nt].x) + kb, 0.f), w2, s0);
            s1 = fmaf(fmaxf(acc[nt][1] + bf2f(qv4[nt].y) + kb, 0.f), w2, s1);
            s2 = fmaf(fmaxf(acc[nt][2] + bf2f(qv4[nt].z) + kb, 0.f), w2, s2);
            s3 = fmaf(fmaxf(acc[nt][3] + bf2f(qv4[nt].w) + kb, 0.f), w2, s3);
        }
        float sr[4] = {s0, s1, s2, s3};
#pragma unroll
        for (int r = 0; r < 4; ++r) {
            float s = sr[r];
            s += __shfl_xor(s, 1);
            s += __shfl_xor(s, 2);
            s += __shfl_xor(s, 4);
            s += __shfl_xor(s, 8);
            if (ln == 0) logits[rbase + quad * 4 + r] = s + b2f;
        }
    }
    __syncthreads();   // logits ready

    // ---- softmax over 256 logits: wave shfl reductions ----
    float lv = logits[t];
    float wm = lv;
#pragma unroll
    for (int d = 1; d < 64; d <<= 1) wm = fmaxf(wm, __shfl_xor(wm, d));
    if (lane == 0) red[wv] = wm;
    __syncthreads();
    float m = fmaxf(fmaxf(red[0], red[1]), fmaxf(red[2], red[3]));
    float e = __expf(lv - m);
    float es = e;
#pragma unroll
    for (int d = 1; d < 64; d <<= 1) es += __shfl_xor(es, d);
    if (lane == 0) red[4 + wv] = es;
    __syncthreads();
    float denom = red[4] + red[5] + red[6] + red[7];
    logits[t] = e / denom;
    __syncthreads();

    // ---- out[n,a,c] = x[n,a,c] + sum_b att[b] * v[n,b,c], float4 over c ----
    {
        int c4 = (t & 31) * 4, bg = t >> 5;          // 8 b-groups of 32
        const float* vp = v + (size_t)(n * PP + bg * 32) * CC + c4;
        float4 av = make_float4(0.f, 0.f, 0.f, 0.f);
#pragma unroll 4
        for (int b = 0; b < 32; ++b) {
            float w = logits[bg * 32 + b];
            float4 vv = *(const float4*)(vp + (size_t)b * CC);
            av.x = fmaf(w, vv.x, av.x); av.y = fmaf(w, vv.y, av.y);
            av.z = fmaf(w, vv.z, av.z); av.w = fmaf(w, vv.w, av.w);
        }
        *(float4*)&avp[bg * 128 + c4] = av;
    }
    __syncthreads();
    if (t < 128) {
        int oidx = (n * PP + a) * CC + t;
        float s = x[oidx];
#pragma unroll
        for (int g = 0; g < 8; ++g) s += avp[g * 128 + t];
        out[oidx] = s;
    }
}

extern "C" void kernel_launch(void* const* d_in, const int* in_sizes, int n_in,
                              void* d_out, int out_size, void* d_ws, size_t ws_size,
                              hipStream_t stream) {
    const float* x   = (const float*)d_in[0];
    const float* pos = (const float*)d_in[1];
    const float* Wq  = (const float*)d_in[2];
    const float* Wk  = (const float*)d_in[3];
    const float* Wv  = (const float*)d_in[4];
    const float* W1  = (const float*)d_in[5];
    const float* b1  = (const float*)d_in[6];
    const float* W2  = (const float*)d_in[7];
    const float* b2  = (const float*)d_in[8];
    const float* Wp1 = (const float*)d_in[9];
    const float* bp1 = (const float*)d_in[10];
    const float* Wp2 = (const float*)d_in[11];
    const float* bp2 = (const float*)d_in[12];
    float* out = (float*)d_out;

    float* ws   = (float*)d_ws;
    float* bvec = ws;                  // 128 f32
    float* kw   = bvec + 128;          // 262144 f32
    float* v    = kw + 262144;         // 262144 f32
    unsigned short* qwtb = (unsigned short*)(v + 262144);  // 262144 bf16
    unsigned short* W21f = qwtb + 262144;                  // 16384 bf16 (frag order)

    stage1_kernel<<<197, 256, 0, stream>>>(x, Wq, Wk, Wv, W1, b1, bp2, Wp2,
                                           qwtb, kw, v, W21f, bvec);
    attn_kernel<<<NB * PP, 256, 0, stream>>>(x, pos, Wp1, bp1, W2, b2,
                                             W21f, bvec, qwtb, kw, v, out);
}